// Round 7
// baseline (204.521 us; speedup 1.0000x reference)
//
#include <hip/hip_runtime.h>
#include <hip/hip_bf16.h>

// SparseMHA, fixed out-degree CSR graph attention. fp32 in/out.
// r6 -> r7: qkv still latency-bound (all pipes <15%, VGPR 84). Root cause:
// A-fragment needs 64 VGPRs of loads but the 84-VGPR allocation forced the
// compiler to issue 4 HBM loads per kt iteration and WAIT inside each of the
// 4 iterations (~3600 exposed cycles/wave). Now all 16 A loads are issued
// up-front into registers; per-kt bf16 conversion reads registers (no memory
// dependence), so each wave stalls once, overlapped across waves.
// attn unchanged from r6 (clean attribution).

typedef unsigned short ushort_t;
typedef unsigned int uint32;
typedef short short8 __attribute__((ext_vector_type(8)));
typedef short short4v __attribute__((ext_vector_type(4)));
typedef float f32x4 __attribute__((ext_vector_type(4)));

#define HID 128
#define DEG 16
#define OSTRIDE_LDS 132   // ushort row stride in LDS repack (bank-conflict-free)

__device__ __forceinline__ float bf2f(ushort_t u) {
  uint32 x = ((uint32)u) << 16;
  return __builtin_bit_cast(float, x);
}
__device__ __forceinline__ ushort_t f2bf(float f) {
  uint32 u = __builtin_bit_cast(uint32, f);
  u += 0x7fffu + ((u >> 16) & 1u);   // RNE
  return (ushort_t)(u >> 16);
}

// Packed split of 2 fp32 -> packed bf16 hi pair + lo pair (RNE, v_cvt_pk path).
__device__ __forceinline__ void split2(float x, float y, uint32& hi, uint32& lo) {
  __hip_bfloat162 h2 = __float22bfloat162_rn(float2{x, y});
  __builtin_memcpy(&hi, &h2, 4);
  float hx = __builtin_bit_cast(float, hi << 16);
  float hy = __builtin_bit_cast(float, hi & 0xffff0000u);
  __hip_bfloat162 l2 = __float22bfloat162_rn(float2{x - hx, y - hy});
  __builtin_memcpy(&lo, &l2, 4);
}

// Two float4 registers (8 consecutive fp32) -> short8 hi + short8 lo.
__device__ __forceinline__ void split8v(float4 a, float4 b, short8& hi, short8& lo) {
  uint32* hu = (uint32*)&hi;
  uint32* lu = (uint32*)&lo;
  split2(a.x, a.y, hu[0], lu[0]);
  split2(a.z, a.w, hu[1], lu[1]);
  split2(b.x, b.y, hu[2], lu[2]);
  split2(b.z, b.w, hu[3], lu[3]);
}

// 8 consecutive fp32 (32B-aligned, via pointer) -> short8 hi + short8 lo.
__device__ __forceinline__ void split8p(const float* __restrict__ p, short8& hi, short8& lo) {
  float4 a = *(const float4*)p;
  float4 b = *(const float4*)(p + 4);
  split8v(a, b, hi, lo);
}

// ---------------- Phase 0: pre-split Wq|Wk|Wv into bf16 hi/lo ----------------
__global__ __launch_bounds__(256) void prep_kernel(
    const float* __restrict__ Wq, const float* __restrict__ Wk,
    const float* __restrict__ Wv,
    ushort_t* __restrict__ whi, ushort_t* __restrict__ wlo) {
  const int idx8 = (blockIdx.x * 256 + threadIdx.x) * 8;   // [0, 49152)
  const float* W = (idx8 < 16384) ? Wq : (idx8 < 32768) ? Wk : Wv;
  const int off = idx8 & 16383;
  short8 hi, lo;
  split8p(W + off, hi, lo);
  *(short8*)(whi + idx8) = hi;
  *(short8*)(wlo + idx8) = lo;
}

// ---------------- Phase 1: Q/K/V projection GEMMs ----------------
// out[i,c] = sum_k h[i,k]*W[c,k] + b[c]; q scaled by 0.25 after bias.
// Grid (ceil(n/128), 3); block 256 = 4 waves; wave computes 32 rows x 128 cols.
// A loads all issued up-front; epilogue repacks via LDS, coalesced 8B stores.
__global__ __launch_bounds__(256) void qkv_kernel(
    const float* __restrict__ h,
    const float* __restrict__ bq, const float* __restrict__ bk,
    const float* __restrict__ bv,
    const ushort_t* __restrict__ whi, const ushort_t* __restrict__ wlo,
    ushort_t* __restrict__ qs, ushort_t* __restrict__ ks, ushort_t* __restrict__ vs,
    int n) {
  __shared__ ushort_t lds_o[4][32 * OSTRIDE_LDS];  // 33 KB

  const int which = blockIdx.y;
  const float* __restrict__ bias = (which == 0) ? bq : (which == 1) ? bk : bv;
  ushort_t* __restrict__ outp = (which == 0) ? qs : (which == 1) ? ks : vs;
  const int ostride = (which == 0) ? 256 : 128;  // q rows live inside 512B fp32 out rows
  const float scale = (which == 0) ? 0.25f : 1.0f;
  const ushort_t* __restrict__ Wh = whi + which * 16384;
  const ushort_t* __restrict__ Wl = wlo + which * 16384;

  const int wave = threadIdx.x >> 6;
  const int l = threadIdx.x & 63;
  const int lm = l & 15;
  const int lq = l >> 4;
  const int m0 = blockIdx.x * 128 + wave * 32;

  int ar0 = m0 + lm;        if (ar0 >= n) ar0 = n - 1;
  int ar1 = m0 + 16 + lm;   if (ar1 >= n) ar1 = n - 1;
  const float* ap0 = h + (size_t)ar0 * HID + lq * 8;
  const float* ap1 = h + (size_t)ar1 * HID + lq * 8;

  // Issue ALL A loads up-front (16 independent dwordx4) — single stall point.
  float4 a0[8], a1[8];
#pragma unroll
  for (int kt = 0; kt < 4; kt++) {
    a0[2 * kt]     = *(const float4*)(ap0 + kt * 32);
    a0[2 * kt + 1] = *(const float4*)(ap0 + kt * 32 + 4);
    a1[2 * kt]     = *(const float4*)(ap1 + kt * 32);
    a1[2 * kt + 1] = *(const float4*)(ap1 + kt * 32 + 4);
  }

  f32x4 acc[2][8];
#pragma unroll
  for (int f = 0; f < 2; f++)
#pragma unroll
    for (int t = 0; t < 8; t++) acc[f][t] = (f32x4){0.f, 0.f, 0.f, 0.f};

#pragma unroll
  for (int kt = 0; kt < 4; kt++) {
    short8 ah0, al0, ah1, al1;   // converted from registers: no memory dep here
    split8v(a0[2 * kt], a0[2 * kt + 1], ah0, al0);
    split8v(a1[2 * kt], a1[2 * kt + 1], ah1, al1);
    const int boff = kt * 32 + lq * 8 + lm * HID;
#pragma unroll
    for (int t = 0; t < 8; t++) {
      short8 bh = *(const short8*)(Wh + t * 16 * HID + boff);
      short8 bl = *(const short8*)(Wl + t * 16 * HID + boff);
      acc[0][t] = __builtin_amdgcn_mfma_f32_16x16x32_bf16(ah0, bh, acc[0][t], 0, 0, 0);
      acc[0][t] = __builtin_amdgcn_mfma_f32_16x16x32_bf16(ah0, bl, acc[0][t], 0, 0, 0);
      acc[0][t] = __builtin_amdgcn_mfma_f32_16x16x32_bf16(al0, bh, acc[0][t], 0, 0, 0);
      acc[1][t] = __builtin_amdgcn_mfma_f32_16x16x32_bf16(ah1, bh, acc[1][t], 0, 0, 0);
      acc[1][t] = __builtin_amdgcn_mfma_f32_16x16x32_bf16(ah1, bl, acc[1][t], 0, 0, 0);
      acc[1][t] = __builtin_amdgcn_mfma_f32_16x16x32_bf16(al1, bh, acc[1][t], 0, 0, 0);
    }
  }

  // Epilogue A: fragments -> LDS (ushort). D[m][c]: c = lm+16t, m = f*16+lq*4+r.
  ushort_t* lo_ = lds_o[wave];
#pragma unroll
  for (int t = 0; t < 8; t++) {
    const int col = t * 16 + lm;
    const float bv_ = bias[col];
#pragma unroll
    for (int f = 0; f < 2; f++) {
#pragma unroll
      for (int r = 0; r < 4; r++) {
        lo_[(f * 16 + lq * 4 + r) * OSTRIDE_LDS + col] = f2bf((acc[f][t][r] + bv_) * scale);
      }
    }
  }
  // Wave-local LDS ordering (region private to this wave).
  asm volatile("s_waitcnt lgkmcnt(0)" ::: "memory");
  __builtin_amdgcn_wave_barrier();

  // Epilogue B: coalesced writeout, 8B/lane, 2 full 256B rows per store inst.
  const int rr = l >> 5;          // 0..1
  const int ch = l & 31;          // 8B chunk index
#pragma unroll
  for (int it = 0; it < 16; it++) {
    const int rw = it * 2 + rr;   // row within wave, 0..31
    const int grow = m0 + rw;
    short4v val = *(short4v*)(lo_ + rw * OSTRIDE_LDS + ch * 4);
    if (grow < n) *(short4v*)(outp + (size_t)grow * ostride + ch * 4) = val;
  }
}

// ---------------- Phase 2: fused scores + softmax + aggregate ----------------
// 2 rows per wave (8 per block). Unchanged from r6.
__global__ __launch_bounds__(256) void attn_kernel(
    const int* __restrict__ col_ind,
    const ushort_t* __restrict__ qs, const ushort_t* __restrict__ ks,
    const ushort_t* __restrict__ vs, float* __restrict__ out, int n) {
  __shared__ __align__(16) float lds_attn[4][2 * DEG * 8];  // 4 KB

  const int wv = threadIdx.x >> 6;
  const int l = threadIdx.x & 63;
  const int lm = l & 15;
  const int lq = l >> 4;

  const int row0 = blockIdx.x * 8 + wv * 2;
  int rowi[2];
  rowi[0] = (row0 < n) ? row0 : n - 1;
  rowi[1] = (row0 + 1 < n) ? row0 + 1 : n - 1;

  short8 af[2][4];
  ushort_t qv[2][4];
  uint32 vreg[2][DEG];

#pragma unroll
  for (int rr = 0; rr < 2; rr++) {
    const int eb = rowi[rr] * DEG;
    const int cm = col_ind[eb + lm];
    const ushort_t* kp = ks + (size_t)cm * HID + lq * 8;
    const ushort_t* qp = qs + (size_t)rowi[rr] * 256;   // q embedded in out row
#pragma unroll
    for (int kt = 0; kt < 4; kt++) {
      af[rr][kt] = *(const short8*)(kp + kt * 32);
      qv[rr][kt] = (lm < 8) ? qp[kt * 32 + lq * 8 + lm] : (ushort_t)0;
    }
#pragma unroll
    for (int e = 0; e < DEG; e++) {
      const int c = col_ind[eb + e];                    // wave-uniform -> s_load
      vreg[rr][e] = *(const uint32*)(vs + (size_t)c * HID + 2 * l);
    }
  }

  f32x4 acc[2] = {(f32x4){0.f, 0.f, 0.f, 0.f}, (f32x4){0.f, 0.f, 0.f, 0.f}};
#pragma unroll
  for (int rr = 0; rr < 2; rr++) {
#pragma unroll
    for (int kt = 0; kt < 4; kt++) {
      short8 bf;
#pragma unroll
      for (int j = 0; j < 8; j++) bf[j] = (lm == j) ? (short)qv[rr][kt] : (short)0;
      acc[rr] = __builtin_amdgcn_mfma_f32_16x16x32_bf16(af[rr][kt], bf, acc[rr], 0, 0, 0);
    }
  }
  // acc[rr][r] = score[edge = lq*4 + r][head = lm]   (lm < 8 valid)

#pragma unroll
  for (int rr = 0; rr < 2; rr++) {
    float m = fmaxf(fmaxf(acc[rr][0], acc[rr][1]), fmaxf(acc[rr][2], acc[rr][3]));
    m = fmaxf(m, __shfl_xor(m, 16, 64));
    m = fmaxf(m, __shfl_xor(m, 32, 64));
    float e0 = __expf(acc[rr][0] - m), e1 = __expf(acc[rr][1] - m);
    float e2 = __expf(acc[rr][2] - m), e3 = __expf(acc[rr][3] - m);
    float s = e0 + e1 + e2 + e3;
    s += __shfl_xor(s, 16, 64);
    s += __shfl_xor(s, 32, 64);
    const float inv = 1.0f / s;
    if (lm < 8) {
      float* ap = &lds_attn[wv][rr * DEG * 8];
      ap[(lq * 4 + 0) * 8 + lm] = e0 * inv;
      ap[(lq * 4 + 1) * 8 + lm] = e1 * inv;
      ap[(lq * 4 + 2) * 8 + lm] = e2 * inv;
      ap[(lq * 4 + 3) * 8 + lm] = e3 * inv;
    }
  }
  // Wave-local LDS ordering (region private to this wave).
  asm volatile("s_waitcnt lgkmcnt(0)" ::: "memory");
  __builtin_amdgcn_wave_barrier();

  const int h0 = 2 * (l & 3);
#pragma unroll
  for (int rr = 0; rr < 2; rr++) {
    const float* ap = &lds_attn[wv][rr * DEG * 8];
    float o0 = 0.f, o1 = 0.f;
#pragma unroll
    for (int e = 0; e < DEG; e++) {
      const float2 at = *(const float2*)(ap + e * 8 + h0);
      o0 += at.x * bf2f((ushort_t)(vreg[rr][e] & 0xffffu));
      o1 += at.y * bf2f((ushort_t)(vreg[rr][e] >> 16));
    }
    float2 o = {o0, o1};
    *(float2*)(out + (size_t)rowi[rr] * HID + 2 * l) = o;  // overwrites consumed q
  }
}

extern "C" void kernel_launch(void* const* d_in, const int* in_sizes, int n_in,
                              void* d_out, int out_size, void* d_ws, size_t ws_size,
                              hipStream_t stream) {
  const float* h  = (const float*)d_in[0];
  const float* Wq = (const float*)d_in[1];
  const float* bq = (const float*)d_in[2];
  const float* Wk = (const float*)d_in[3];
  const float* bk = (const float*)d_in[4];
  const float* Wv = (const float*)d_in[5];
  const float* bv = (const float*)d_in[6];
  // d_in[7] = row_ptr (fixed degree 16) — unused
  const int* col_ind = (const int*)d_in[8];
  // d_in[9] = num_heads (= 8) — hardcoded in layout math

  const int n = in_sizes[0] / HID;  // 50000

  // ws layout (~25.8 MB): k, v bf16 tables + W hi/lo splits. q (bf16) lives in
  // the first 256 B of each row's 512 B fp32 out slot.
  ushort_t* ks  = (ushort_t*)d_ws;
  ushort_t* vs  = ks + (size_t)n * HID;
  ushort_t* whi = vs + (size_t)n * HID;
  ushort_t* wlo = whi + 3 * 16384;
  ushort_t* qs  = (ushort_t*)d_out;
  float* outf   = (float*)d_out;

  prep_kernel<<<24, 256, 0, stream>>>(Wq, Wk, Wv, whi, wlo);
  dim3 g1((n + 127) / 128, 3);
  qkv_kernel<<<g1, 256, 0, stream>>>(h, bq, bk, bv, whi, wlo, qs, ks, vs, n);
  attn_kernel<<<(n + 7) / 8, 256, 0, stream>>>(col_ind, qs, ks, vs, outf, n);
}

// Round 8
// 199.403 us; speedup vs baseline: 1.0257x; 1.0257x over previous
//
#include <hip/hip_runtime.h>
#include <hip/hip_bf16.h>

// SparseMHA, fixed out-degree CSR graph attention. fp32 in/out.
// r7 -> r8: r7's source-level A-prefetch was a codegen no-op (identical VGPR
// count & dur) — the compiler re-sinks loads. qkv runs at a stable 1.15 TB/s
// achieved HBM BW with all pipes <15%: too few outstanding requests. Fix via
// __builtin_amdgcn_global_load_lds (async DMA the compiler can't reorder
// away): 16 x 16B per wave issued back-to-back, one vmcnt(0), then MFMA from
// LDS (chunk-major slots = bank-balanced ds_read_b128). LDS reused for the
// store-repack epilogue. attn reverted to 1 row/wave (r6's 2-row was +5.6us).

typedef unsigned short ushort_t;
typedef unsigned int uint32;
typedef short short8 __attribute__((ext_vector_type(8)));
typedef short short4v __attribute__((ext_vector_type(4)));
typedef float f32x4 __attribute__((ext_vector_type(4)));

#define HID 128
#define DEG 16
#define OSTRIDE_LDS 132   // ushort row stride in LDS repack (bank-conflict-free)

__device__ __forceinline__ float bf2f(ushort_t u) {
  uint32 x = ((uint32)u) << 16;
  return __builtin_bit_cast(float, x);
}
__device__ __forceinline__ ushort_t f2bf(float f) {
  uint32 u = __builtin_bit_cast(uint32, f);
  u += 0x7fffu + ((u >> 16) & 1u);   // RNE
  return (ushort_t)(u >> 16);
}

// Packed split of 2 fp32 -> packed bf16 hi pair + lo pair (RNE, v_cvt_pk path).
__device__ __forceinline__ void split2(float x, float y, uint32& hi, uint32& lo) {
  __hip_bfloat162 h2 = __float22bfloat162_rn(float2{x, y});
  __builtin_memcpy(&hi, &h2, 4);
  float hx = __builtin_bit_cast(float, hi << 16);
  float hy = __builtin_bit_cast(float, hi & 0xffff0000u);
  __hip_bfloat162 l2 = __float22bfloat162_rn(float2{x - hx, y - hy});
  __builtin_memcpy(&lo, &l2, 4);
}

// Two float4 registers (8 consecutive fp32) -> short8 hi + short8 lo.
__device__ __forceinline__ void split8v(float4 a, float4 b, short8& hi, short8& lo) {
  uint32* hu = (uint32*)&hi;
  uint32* lu = (uint32*)&lo;
  split2(a.x, a.y, hu[0], lu[0]);
  split2(a.z, a.w, hu[1], lu[1]);
  split2(b.x, b.y, hu[2], lu[2]);
  split2(b.z, b.w, hu[3], lu[3]);
}

// 8 consecutive fp32 (32B-aligned, via pointer) -> short8 hi + short8 lo.
__device__ __forceinline__ void split8p(const float* __restrict__ p, short8& hi, short8& lo) {
  float4 a = *(const float4*)p;
  float4 b = *(const float4*)(p + 4);
  split8v(a, b, hi, lo);
}

// ---------------- Phase 0: pre-split Wq|Wk|Wv into bf16 hi/lo ----------------
__global__ __launch_bounds__(256) void prep_kernel(
    const float* __restrict__ Wq, const float* __restrict__ Wk,
    const float* __restrict__ Wv,
    ushort_t* __restrict__ whi, ushort_t* __restrict__ wlo) {
  const int idx8 = (blockIdx.x * 256 + threadIdx.x) * 8;   // [0, 49152)
  const float* W = (idx8 < 16384) ? Wq : (idx8 < 32768) ? Wk : Wv;
  const int off = idx8 & 16383;
  short8 hi, lo;
  split8p(W + off, hi, lo);
  *(short8*)(whi + idx8) = hi;
  *(short8*)(wlo + idx8) = lo;
}

// ---------------- Phase 1: Q/K/V projection GEMMs ----------------
// out[i,c] = sum_k h[i,k]*W[c,k] + b[c]; q scaled by 0.25 after bias.
// Grid (ceil(n/128), 3); block 256 = 4 waves; wave computes 32 rows x 128 cols.
// h tile staged to LDS via global_load_lds (16 async 16B DMAs per wave, one
// vmcnt(0) stall). Chunk-major slots: slot s = c*32 + r (c = 16B chunk 0..31
// within row, r = row 0..31); inst j covers slots j*64 + lane.
__global__ __launch_bounds__(256) void qkv_kernel(
    const float* __restrict__ h,
    const float* __restrict__ bq, const float* __restrict__ bk,
    const float* __restrict__ bv,
    const ushort_t* __restrict__ whi, const ushort_t* __restrict__ wlo,
    ushort_t* __restrict__ qs, ushort_t* __restrict__ ks, ushort_t* __restrict__ vs,
    int n) {
  __shared__ __align__(16) float4 lds_f4[4][1024];   // 64 KB; per-wave 16 KB

  const int which = blockIdx.y;
  const float* __restrict__ bias = (which == 0) ? bq : (which == 1) ? bk : bv;
  ushort_t* __restrict__ outp = (which == 0) ? qs : (which == 1) ? ks : vs;
  const int ostride = (which == 0) ? 256 : 128;  // q rows live inside 512B fp32 out rows
  const float scale = (which == 0) ? 0.25f : 1.0f;
  const ushort_t* __restrict__ Wh = whi + which * 16384;
  const ushort_t* __restrict__ Wl = wlo + which * 16384;

  const int wave = threadIdx.x >> 6;
  const int l = threadIdx.x & 63;
  const int lm = l & 15;
  const int lq = l >> 4;
  const int m0 = blockIdx.x * 128 + wave * 32;

  // --- async stage: 16 global_load_lds (all outstanding simultaneously) ---
  {
    const int r = l & 31;           // row within wave tile
    const int chalf = l >> 5;       // which of 2 chunks this inst covers
    int grow = m0 + r; if (grow >= n) grow = n - 1;   // ragged-tail clamp
    const float* gbase = h + (size_t)grow * HID;
    char* lbase = (char*)&lds_f4[wave][0];
#pragma unroll
    for (int j = 0; j < 16; j++) {
      const int c = j * 2 + chalf;  // chunk index 0..31
      const float* gp = gbase + c * 4;
      // per-lane lds ptr = base + j*1024 + l*16 (consistent with HW lane*size)
      __builtin_amdgcn_global_load_lds(
          (const __attribute__((address_space(1))) void*)gp,
          (__attribute__((address_space(3))) void*)(lbase + j * 1024 + l * 16),
          16, 0, 0);
    }
  }
  asm volatile("s_waitcnt vmcnt(0)" ::: "memory");
  __builtin_amdgcn_wave_barrier();

  const float4* lw = &lds_f4[wave][0];

  f32x4 acc[2][8];
#pragma unroll
  for (int f = 0; f < 2; f++)
#pragma unroll
    for (int t = 0; t < 8; t++) acc[f][t] = (f32x4){0.f, 0.f, 0.f, 0.f};

#pragma unroll
  for (int kt = 0; kt < 4; kt++) {
    const int c0 = kt * 8 + lq * 2;            // chunk of k-offset lq*8
    float4 x0 = lw[(c0 + 0) * 32 + lm];        // rows 0..15 fragment
    float4 y0 = lw[(c0 + 1) * 32 + lm];
    float4 x1 = lw[(c0 + 0) * 32 + 16 + lm];   // rows 16..31 fragment
    float4 y1 = lw[(c0 + 1) * 32 + 16 + lm];
    short8 ah0, al0, ah1, al1;
    split8v(x0, y0, ah0, al0);
    split8v(x1, y1, ah1, al1);
    const int boff = kt * 32 + lq * 8 + lm * HID;
#pragma unroll
    for (int t = 0; t < 8; t++) {
      short8 bh = *(const short8*)(Wh + t * 16 * HID + boff);
      short8 bl = *(const short8*)(Wl + t * 16 * HID + boff);
      acc[0][t] = __builtin_amdgcn_mfma_f32_16x16x32_bf16(ah0, bh, acc[0][t], 0, 0, 0);
      acc[0][t] = __builtin_amdgcn_mfma_f32_16x16x32_bf16(ah0, bl, acc[0][t], 0, 0, 0);
      acc[0][t] = __builtin_amdgcn_mfma_f32_16x16x32_bf16(al0, bh, acc[0][t], 0, 0, 0);
      acc[1][t] = __builtin_amdgcn_mfma_f32_16x16x32_bf16(ah1, bh, acc[1][t], 0, 0, 0);
      acc[1][t] = __builtin_amdgcn_mfma_f32_16x16x32_bf16(ah1, bl, acc[1][t], 0, 0, 0);
      acc[1][t] = __builtin_amdgcn_mfma_f32_16x16x32_bf16(al1, bh, acc[1][t], 0, 0, 0);
    }
  }

  // Epilogue A: fragments -> LDS (reusing the staging region; all A-fragment
  // ds_reads precede these ds_writes in wave program order). D[m][c]: c =
  // lm+16t, m = f*16+lq*4+r.
  ushort_t* lo_ = (ushort_t*)lw;
#pragma unroll
  for (int t = 0; t < 8; t++) {
    const int col = t * 16 + lm;
    const float bv_ = bias[col];
#pragma unroll
    for (int f = 0; f < 2; f++) {
#pragma unroll
      for (int r = 0; r < 4; r++) {
        lo_[(f * 16 + lq * 4 + r) * OSTRIDE_LDS + col] = f2bf((acc[f][t][r] + bv_) * scale);
      }
    }
  }
  // Wave-local LDS ordering (region private to this wave).
  asm volatile("s_waitcnt lgkmcnt(0)" ::: "memory");
  __builtin_amdgcn_wave_barrier();

  // Epilogue B: coalesced writeout, 8B/lane, 2 full 256B rows per store inst.
  const int rr = l >> 5;          // 0..1
  const int ch = l & 31;          // 8B chunk index
#pragma unroll
  for (int it = 0; it < 16; it++) {
    const int rw = it * 2 + rr;   // row within wave, 0..31
    const int grow = m0 + rw;
    short4v val = *(short4v*)(lo_ + rw * OSTRIDE_LDS + ch * 4);
    if (grow < n) *(short4v*)(outp + (size_t)grow * ostride + ch * 4) = val;
  }
}

// ---------------- Phase 2: fused scores + softmax + aggregate ----------------
// One wave per row (r5 config — r6's 2-rows/wave measured +5.6us, reverted).
// Scores via MFMA (gathered K rows as A, diagonal-expanded q as B); V
// prefetched into registers before softmax; per-wave-private LDS ordering.
__global__ __launch_bounds__(256) void attn_kernel(
    const int* __restrict__ col_ind,
    const ushort_t* __restrict__ qs, const ushort_t* __restrict__ ks,
    const ushort_t* __restrict__ vs, float* __restrict__ out, int n) {
  __shared__ __align__(16) float lds_attn[4 * DEG * 8];  // [wave][edge][head]

  const int wv = threadIdx.x >> 6;
  const int l = threadIdx.x & 63;
  const int lm = l & 15;
  const int lq = l >> 4;

  int row = blockIdx.x * 4 + wv;
  if (row >= n) row = n - 1;
  const int eb = row * DEG;

  const int cm = col_ind[eb + lm];                 // this lane's A-operand edge
  const ushort_t* kp = ks + (size_t)cm * HID + lq * 8;
  const ushort_t* qp = qs + (size_t)row * 256;     // q embedded in out row

  short8 af[4];
  ushort_t qv[4];
#pragma unroll
  for (int kt = 0; kt < 4; kt++) {
    af[kt] = *(const short8*)(kp + kt * 32);
    qv[kt] = (lm < 8) ? qp[kt * 32 + lq * 8 + lm] : (ushort_t)0;
  }

  // Prefetch all V words (independent of scores; hides behind MFMA+softmax).
  uint32 vreg[DEG];
#pragma unroll
  for (int e = 0; e < DEG; e++) {
    const int c = col_ind[eb + e];                 // wave-uniform -> s_load
    vreg[e] = *(const uint32*)(vs + (size_t)c * HID + 2 * l);
  }

  f32x4 acc = (f32x4){0.f, 0.f, 0.f, 0.f};
#pragma unroll
  for (int kt = 0; kt < 4; kt++) {
    short8 bf;
#pragma unroll
    for (int j = 0; j < 8; j++) bf[j] = (lm == j) ? (short)qv[kt] : (short)0;
    acc = __builtin_amdgcn_mfma_f32_16x16x32_bf16(af[kt], bf, acc, 0, 0, 0);
  }
  // acc[r] = score[edge = lq*4 + r][head = lm]   (lm < 8 valid)

  float m = fmaxf(fmaxf(acc[0], acc[1]), fmaxf(acc[2], acc[3]));
  m = fmaxf(m, __shfl_xor(m, 16, 64));
  m = fmaxf(m, __shfl_xor(m, 32, 64));
  float e0 = __expf(acc[0] - m), e1 = __expf(acc[1] - m);
  float e2 = __expf(acc[2] - m), e3 = __expf(acc[3] - m);
  float s = e0 + e1 + e2 + e3;
  s += __shfl_xor(s, 16, 64);
  s += __shfl_xor(s, 32, 64);
  const float inv = 1.0f / s;

  float* ap = &lds_attn[wv * (DEG * 8)];
  if (lm < 8) {
    ap[(lq * 4 + 0) * 8 + lm] = e0 * inv;
    ap[(lq * 4 + 1) * 8 + lm] = e1 * inv;
    ap[(lq * 4 + 2) * 8 + lm] = e2 * inv;
    ap[(lq * 4 + 3) * 8 + lm] = e3 * inv;
  }
  asm volatile("s_waitcnt lgkmcnt(0)" ::: "memory");
  __builtin_amdgcn_wave_barrier();

  const int h0 = 2 * (l & 3);
  float o0 = 0.f, o1 = 0.f;
#pragma unroll
  for (int e = 0; e < DEG; e++) {
    const float2 at = *(const float2*)(ap + e * 8 + h0);
    o0 += at.x * bf2f((ushort_t)(vreg[e] & 0xffffu));
    o1 += at.y * bf2f((ushort_t)(vreg[e] >> 16));
  }

  float2 o = {o0, o1};
  *(float2*)(out + (size_t)row * HID + 2 * l) = o;  // overwrites consumed q
}

extern "C" void kernel_launch(void* const* d_in, const int* in_sizes, int n_in,
                              void* d_out, int out_size, void* d_ws, size_t ws_size,
                              hipStream_t stream) {
  const float* h  = (const float*)d_in[0];
  const float* Wq = (const float*)d_in[1];
  const float* bq = (const float*)d_in[2];
  const float* Wk = (const float*)d_in[3];
  const float* bk = (const float*)d_in[4];
  const float* Wv = (const float*)d_in[5];
  const float* bv = (const float*)d_in[6];
  // d_in[7] = row_ptr (fixed degree 16) — unused
  const int* col_ind = (const int*)d_in[8];
  // d_in[9] = num_heads (= 8) — hardcoded in layout math

  const int n = in_sizes[0] / HID;  // 50000

  // ws layout (~25.8 MB): k, v bf16 tables + W hi/lo splits. q (bf16) lives in
  // the first 256 B of each row's 512 B fp32 out slot.
  ushort_t* ks  = (ushort_t*)d_ws;
  ushort_t* vs  = ks + (size_t)n * HID;
  ushort_t* whi = vs + (size_t)n * HID;
  ushort_t* wlo = whi + 3 * 16384;
  ushort_t* qs  = (ushort_t*)d_out;
  float* outf   = (float*)d_out;

  prep_kernel<<<24, 256, 0, stream>>>(Wq, Wk, Wv, whi, wlo);
  dim3 g1((n + 127) / 128, 3);
  qkv_kernel<<<g1, 256, 0, stream>>>(h, bq, bk, bv, whi, wlo, qs, ks, vs, n);
  attn_kernel<<<(n + 3) / 4, 256, 0, stream>>>(col_ind, qs, ks, vs, outf, n);
}

// Round 9
// 172.153 us; speedup vs baseline: 1.1880x; 1.1583x over previous
//
#include <hip/hip_runtime.h>
#include <hip/hip_bf16.h>

// SparseMHA, fixed out-degree CSR graph attention. fp32 in/out.
// r8 -> r9: three different A-paths (r6/r7/r8) gave byte-identical qkv time
// (68us, 1.15TB/s, all pipes idle) -> the constant was the B-path: every wave
// streamed 64KB of W-splits from global (L1-thrashing, L2-latency-serialized).
// Now ONE fused kernel does q,k,v per 128-row tile; B is DMA'd into a 32KB
// LDS buffer once per block per hi/lo phase (6 phases), stored in exact
// fragment order -> conflict-free ds_read_b128; h loaded+split ONCE (was 3x).
// attn unchanged from r8.

typedef unsigned short ushort_t;
typedef unsigned int uint32;
typedef short short8 __attribute__((ext_vector_type(8)));
typedef short short4v __attribute__((ext_vector_type(4)));
typedef float f32x4 __attribute__((ext_vector_type(4)));

#define HID 128
#define DEG 16
#define OSTRIDE_LDS 132   // ushort row stride in LDS repack (bank-conflict-free)

__device__ __forceinline__ float bf2f(ushort_t u) {
  uint32 x = ((uint32)u) << 16;
  return __builtin_bit_cast(float, x);
}
__device__ __forceinline__ ushort_t f2bf(float f) {
  uint32 u = __builtin_bit_cast(uint32, f);
  u += 0x7fffu + ((u >> 16) & 1u);   // RNE
  return (ushort_t)(u >> 16);
}

// Packed split of 2 fp32 -> packed bf16 hi pair + lo pair (RNE, v_cvt_pk path).
__device__ __forceinline__ void split2(float x, float y, uint32& hi, uint32& lo) {
  __hip_bfloat162 h2 = __float22bfloat162_rn(float2{x, y});
  __builtin_memcpy(&hi, &h2, 4);
  float hx = __builtin_bit_cast(float, hi << 16);
  float hy = __builtin_bit_cast(float, hi & 0xffff0000u);
  __hip_bfloat162 l2 = __float22bfloat162_rn(float2{x - hx, y - hy});
  __builtin_memcpy(&lo, &l2, 4);
}

__device__ __forceinline__ void split8v(float4 a, float4 b, short8& hi, short8& lo) {
  uint32* hu = (uint32*)&hi;
  uint32* lu = (uint32*)&lo;
  split2(a.x, a.y, hu[0], lu[0]);
  split2(a.z, a.w, hu[1], lu[1]);
  split2(b.x, b.y, hu[2], lu[2]);
  split2(b.z, b.w, hu[3], lu[3]);
}

__device__ __forceinline__ void split8p(const float* __restrict__ p, short8& hi, short8& lo) {
  float4 a = *(const float4*)p;
  float4 b = *(const float4*)(p + 4);
  split8v(a, b, hi, lo);
}

// ---------------- Phase 0: pre-split Wq|Wk|Wv into bf16 hi/lo ----------------
__global__ __launch_bounds__(256) void prep_kernel(
    const float* __restrict__ Wq, const float* __restrict__ Wk,
    const float* __restrict__ Wv,
    ushort_t* __restrict__ whi, ushort_t* __restrict__ wlo) {
  const int idx8 = (blockIdx.x * 256 + threadIdx.x) * 8;   // [0, 49152)
  const float* W = (idx8 < 16384) ? Wq : (idx8 < 32768) ? Wk : Wv;
  const int off = idx8 & 16383;
  short8 hi, lo;
  split8p(W + off, hi, lo);
  *(short8*)(whi + idx8) = hi;
  *(short8*)(wlo + idx8) = lo;
}

// ---------------- Phase 1: fused Q+K+V projection ----------------
// One block = 128 rows (4 waves x 32 rows, 2 A-fragments each). For each of
// the 3 projections: DMA Wh fragments -> LDS (32KB, exact lane order), sync,
// MFMA (ah*bh, al*bh), sync, DMA Wl over same buffer, sync, MFMA (ah*bl),
// sync; then per-wave LDS repack -> coalesced 8B/lane stores.
// B fragment slot j = t*4+kt (1KB each): lane l holds bytes j*1024 + l*16.
__global__ __launch_bounds__(256) void qkv_fused_kernel(
    const float* __restrict__ h,
    const float* __restrict__ bq, const float* __restrict__ bk,
    const float* __restrict__ bv,
    const ushort_t* __restrict__ whi, const ushort_t* __restrict__ wlo,
    ushort_t* __restrict__ qs, ushort_t* __restrict__ ks, ushort_t* __restrict__ vs,
    int n) {
  __shared__ __align__(16) char lds_b[32 * 1024];            // B fragments (reused 6x)
  __shared__ ushort_t lds_r[4][32 * OSTRIDE_LDS];            // repack, 33 KB

  const int wave = threadIdx.x >> 6;
  const int l = threadIdx.x & 63;
  const int lm = l & 15;
  const int lq = l >> 4;
  const int m0 = blockIdx.x * 128 + wave * 32;

  // --- A: load h rows and split to bf16 hi/lo ONCE; reused by all 3 projections.
  int ar0 = m0 + lm;        if (ar0 >= n) ar0 = n - 1;
  int ar1 = m0 + 16 + lm;   if (ar1 >= n) ar1 = n - 1;
  const float* ap0 = h + (size_t)ar0 * HID + lq * 8;
  const float* ap1 = h + (size_t)ar1 * HID + lq * 8;
  short8 ah0[4], al0[4], ah1[4], al1[4];
#pragma unroll
  for (int kt = 0; kt < 4; kt++) {
    split8p(ap0 + kt * 32, ah0[kt], al0[kt]);
    split8p(ap1 + kt * 32, ah1[kt], al1[kt]);
  }

#pragma unroll 1
  for (int p = 0; p < 3; p++) {
    const ushort_t* __restrict__ Wh = whi + p * 16384;
    const ushort_t* __restrict__ Wl = wlo + p * 16384;
    const float* __restrict__ bias = (p == 0) ? bq : (p == 1) ? bk : bv;
    ushort_t* __restrict__ outp = (p == 0) ? qs : (p == 1) ? ks : vs;
    const int ostride = (p == 0) ? 256 : 128;   // q lives inside 512B fp32 out rows
    const float scale = (p == 0) ? 0.25f : 1.0f;

    f32x4 acc[2][8];
#pragma unroll
    for (int f = 0; f < 2; f++)
#pragma unroll
      for (int t = 0; t < 8; t++) acc[f][t] = (f32x4){0.f, 0.f, 0.f, 0.f};

    // ---- hi phase ----
#pragma unroll
    for (int jj = 0; jj < 8; jj++) {            // wave covers j = wave*8 + jj
      const int j = wave * 8 + jj, t = j >> 2, kt = j & 3;
      const ushort_t* gp = Wh + (t * 16 + lm) * HID + kt * 32 + lq * 8;
      __builtin_amdgcn_global_load_lds(
          (const __attribute__((address_space(1))) void*)gp,
          (__attribute__((address_space(3))) void*)(lds_b + j * 1024 + l * 16),
          16, 0, 0);
    }
    __syncthreads();                             // DMA drained for all waves
#pragma unroll
    for (int kt = 0; kt < 4; kt++) {
#pragma unroll
      for (int t = 0; t < 8; t++) {
        short8 bh = *(const short8*)(lds_b + (t * 4 + kt) * 1024 + l * 16);
        acc[0][t] = __builtin_amdgcn_mfma_f32_16x16x32_bf16(ah0[kt], bh, acc[0][t], 0, 0, 0);
        acc[0][t] = __builtin_amdgcn_mfma_f32_16x16x32_bf16(al0[kt], bh, acc[0][t], 0, 0, 0);
        acc[1][t] = __builtin_amdgcn_mfma_f32_16x16x32_bf16(ah1[kt], bh, acc[1][t], 0, 0, 0);
        acc[1][t] = __builtin_amdgcn_mfma_f32_16x16x32_bf16(al1[kt], bh, acc[1][t], 0, 0, 0);
      }
    }
    __syncthreads();                             // all waves done reading hi

    // ---- lo phase (overwrites lds_b) ----
#pragma unroll
    for (int jj = 0; jj < 8; jj++) {
      const int j = wave * 8 + jj, t = j >> 2, kt = j & 3;
      const ushort_t* gp = Wl + (t * 16 + lm) * HID + kt * 32 + lq * 8;
      __builtin_amdgcn_global_load_lds(
          (const __attribute__((address_space(1))) void*)gp,
          (__attribute__((address_space(3))) void*)(lds_b + j * 1024 + l * 16),
          16, 0, 0);
    }
    __syncthreads();
#pragma unroll
    for (int kt = 0; kt < 4; kt++) {
#pragma unroll
      for (int t = 0; t < 8; t++) {
        short8 bl = *(const short8*)(lds_b + (t * 4 + kt) * 1024 + l * 16);
        acc[0][t] = __builtin_amdgcn_mfma_f32_16x16x32_bf16(ah0[kt], bl, acc[0][t], 0, 0, 0);
        acc[1][t] = __builtin_amdgcn_mfma_f32_16x16x32_bf16(ah1[kt], bl, acc[1][t], 0, 0, 0);
      }
    }
    __syncthreads();                             // protect lds_b for next projection

    // ---- epilogue: fragments -> per-wave LDS repack -> coalesced stores ----
    ushort_t* lo_ = lds_r[wave];
#pragma unroll
    for (int t = 0; t < 8; t++) {
      const int col = t * 16 + lm;
      const float bv_ = bias[col];
#pragma unroll
      for (int f = 0; f < 2; f++) {
#pragma unroll
        for (int r = 0; r < 4; r++) {
          lo_[(f * 16 + lq * 4 + r) * OSTRIDE_LDS + col] = f2bf((acc[f][t][r] + bv_) * scale);
        }
      }
    }
    asm volatile("s_waitcnt lgkmcnt(0)" ::: "memory");   // wave-local ordering
    __builtin_amdgcn_wave_barrier();

    const int rr = l >> 5;
    const int ch = l & 31;
#pragma unroll
    for (int it = 0; it < 16; it++) {
      const int rw = it * 2 + rr;                // row within wave, 0..31
      const int grow = m0 + rw;
      short4v val = *(short4v*)(lo_ + rw * OSTRIDE_LDS + ch * 4);
      if (grow < n) *(short4v*)(outp + (size_t)grow * ostride + ch * 4) = val;
    }
  }
}

// ---------------- Phase 2: fused scores + softmax + aggregate ----------------
// One wave per row (unchanged from r8).
__global__ __launch_bounds__(256) void attn_kernel(
    const int* __restrict__ col_ind,
    const ushort_t* __restrict__ qs, const ushort_t* __restrict__ ks,
    const ushort_t* __restrict__ vs, float* __restrict__ out, int n) {
  __shared__ __align__(16) float lds_attn[4 * DEG * 8];  // [wave][edge][head]

  const int wv = threadIdx.x >> 6;
  const int l = threadIdx.x & 63;
  const int lm = l & 15;
  const int lq = l >> 4;

  int row = blockIdx.x * 4 + wv;
  if (row >= n) row = n - 1;
  const int eb = row * DEG;

  const int cm = col_ind[eb + lm];                 // this lane's A-operand edge
  const ushort_t* kp = ks + (size_t)cm * HID + lq * 8;
  const ushort_t* qp = qs + (size_t)row * 256;     // q embedded in out row

  short8 af[4];
  ushort_t qv[4];
#pragma unroll
  for (int kt = 0; kt < 4; kt++) {
    af[kt] = *(const short8*)(kp + kt * 32);
    qv[kt] = (lm < 8) ? qp[kt * 32 + lq * 8 + lm] : (ushort_t)0;
  }

  uint32 vreg[DEG];
#pragma unroll
  for (int e = 0; e < DEG; e++) {
    const int c = col_ind[eb + e];                 // wave-uniform -> s_load
    vreg[e] = *(const uint32*)(vs + (size_t)c * HID + 2 * l);
  }

  f32x4 acc = (f32x4){0.f, 0.f, 0.f, 0.f};
#pragma unroll
  for (int kt = 0; kt < 4; kt++) {
    short8 bf;
#pragma unroll
    for (int j = 0; j < 8; j++) bf[j] = (lm == j) ? (short)qv[kt] : (short)0;
    acc = __builtin_amdgcn_mfma_f32_16x16x32_bf16(af[kt], bf, acc, 0, 0, 0);
  }

  float m = fmaxf(fmaxf(acc[0], acc[1]), fmaxf(acc[2], acc[3]));
  m = fmaxf(m, __shfl_xor(m, 16, 64));
  m = fmaxf(m, __shfl_xor(m, 32, 64));
  float e0 = __expf(acc[0] - m), e1 = __expf(acc[1] - m);
  float e2 = __expf(acc[2] - m), e3 = __expf(acc[3] - m);
  float s = e0 + e1 + e2 + e3;
  s += __shfl_xor(s, 16, 64);
  s += __shfl_xor(s, 32, 64);
  const float inv = 1.0f / s;

  float* ap = &lds_attn[wv * (DEG * 8)];
  if (lm < 8) {
    ap[(lq * 4 + 0) * 8 + lm] = e0 * inv;
    ap[(lq * 4 + 1) * 8 + lm] = e1 * inv;
    ap[(lq * 4 + 2) * 8 + lm] = e2 * inv;
    ap[(lq * 4 + 3) * 8 + lm] = e3 * inv;
  }
  asm volatile("s_waitcnt lgkmcnt(0)" ::: "memory");
  __builtin_amdgcn_wave_barrier();

  const int h0 = 2 * (l & 3);
  float o0 = 0.f, o1 = 0.f;
#pragma unroll
  for (int e = 0; e < DEG; e++) {
    const float2 at = *(const float2*)(ap + e * 8 + h0);
    o0 += at.x * bf2f((ushort_t)(vreg[e] & 0xffffu));
    o1 += at.y * bf2f((ushort_t)(vreg[e] >> 16));
  }

  float2 o = {o0, o1};
  *(float2*)(out + (size_t)row * HID + 2 * l) = o;  // overwrites consumed q
}

extern "C" void kernel_launch(void* const* d_in, const int* in_sizes, int n_in,
                              void* d_out, int out_size, void* d_ws, size_t ws_size,
                              hipStream_t stream) {
  const float* h  = (const float*)d_in[0];
  const float* Wq = (const float*)d_in[1];
  const float* bq = (const float*)d_in[2];
  const float* Wk = (const float*)d_in[3];
  const float* bk = (const float*)d_in[4];
  const float* Wv = (const float*)d_in[5];
  const float* bv = (const float*)d_in[6];
  // d_in[7] = row_ptr (fixed degree 16) — unused
  const int* col_ind = (const int*)d_in[8];
  // d_in[9] = num_heads (= 8) — hardcoded in layout math

  const int n = in_sizes[0] / HID;  // 50000

  // ws layout (~25.8 MB): k, v bf16 tables + W hi/lo splits. q (bf16) lives in
  // the first 256 B of each row's 512 B fp32 out slot.
  ushort_t* ks  = (ushort_t*)d_ws;
  ushort_t* vs  = ks + (size_t)n * HID;
  ushort_t* whi = vs + (size_t)n * HID;
  ushort_t* wlo = whi + 3 * 16384;
  ushort_t* qs  = (ushort_t*)d_out;
  float* outf   = (float*)d_out;

  prep_kernel<<<24, 256, 0, stream>>>(Wq, Wk, Wv, whi, wlo);
  qkv_fused_kernel<<<(n + 127) / 128, 256, 0, stream>>>(h, bq, bk, bv, whi, wlo, qs, ks, vs, n);
  attn_kernel<<<(n + 3) / 4, 256, 0, stream>>>(col_ind, qs, ks, vs, outf, n);
}